// Round 2
// baseline (176.683 us; speedup 1.0000x reference)
//
#include <hip/hip_runtime.h>
#include <hip/hip_bf16.h>

#define BATCH 1024
#define SEQ 256
#define HIDDEN 128
#define VOCAB 60
#define ROWS 4             // real batch rows per block (MFMA n-dim aliased 4x)
#define ASTRIDE 144        // f16 per h row: 72 dw == 8 mod 32 -> max 2-way (free)
#define XSTR (SEQ + 4)     // 260 ints = 1040 B: keeps int2 token reads 8B-aligned

typedef _Float16 f16x8 __attribute__((ext_vector_type(8)));
typedef float f32x4 __attribute__((ext_vector_type(4)));

__device__ __forceinline__ float fast_tanh(float x) {
    // tanh(x) = 1 - 2/(exp(2x)+1); exp(2x)=exp2(x*2*log2e). Branch-free, exact +-1 tails.
    float e = __builtin_amdgcn_exp2f(x * 2.8853900817779268f);
    return __builtin_fmaf(-2.0f, __builtin_amdgcn_rcpf(e + 1.0f), 1.0f);
}

__device__ __forceinline__ f32x4 MF(f16x8 a, f16x8 b, f32x4 c) {
    return __builtin_amdgcn_mfma_f32_16x16x32_f16(a, b, c, 0, 0, 0);
}

// embW[v][i] = sum_j emb[v][j] * W_ih[i][j]  (fp32-exact input-projection table)
__global__ void rnn_prep_embw(const float* __restrict__ emb,
                              const float* __restrict__ W_ih,
                              float* __restrict__ embW) {
    const int v = blockIdx.x;
    const int i = threadIdx.x;
    __shared__ __align__(16) float e[HIDDEN];
    e[i] = emb[v * HIDDEN + i];
    __syncthreads();
    const float4* wrow = (const float4*)(W_ih + i * HIDDEN);
    const float4* e4 = (const float4*)e;
    float a0 = 0.f, a1 = 0.f, a2 = 0.f, a3 = 0.f;
#pragma unroll
    for (int j = 0; j < HIDDEN / 4; ++j) {
        float4 w = wrow[j];
        float4 h = e4[j];
        a0 += w.x * h.x; a1 += w.y * h.y; a2 += w.z * h.z; a3 += w.w * h.w;
    }
    embW[v * HIDDEN + i] = (a0 + a1) + (a2 + a3);
}

// R17 structure: 256 blocks x 256 threads (4 waves, 1/SIMD), 4 batch rows per
// block, 1 block/CU. Transposed recurrence z^T = W_hh * h^T; wave w owns TWO
// 16-col MFMA groups (cols [32w, 32w+32)) which SHARE one set of h B-frags:
// per-step broadcast H-reads drop from 32 ops (8 waves x 4) to 16 (4 x 4).
// The ring/chunk seed machinery is deleted: per-step C-init comes straight
// from L2-resident embW via per-lane f32x4 VMEM loads prefetched 2 steps
// ahead (named regs, unroll-2) -- the seed path leaves the contended DS pipe
// entirely. MFMA n-dim (16) aliases the 4 real rows 4x (broadcast reads,
// free); only r16<4 lanes write h.
__global__ void __launch_bounds__(256)
rnn_mfma(const int* __restrict__ x, const int* __restrict__ lengths,
         const float* __restrict__ embW, const float* __restrict__ W_hh,
         const float* __restrict__ W_fc, const float* __restrict__ b_fc,
         float* __restrict__ out) {
    const int tid = threadIdx.x;
    const int wave = tid >> 6;   // 0..3
    const int lane = tid & 63;
    const int q = lane >> 4;     // 0..3
    const int r16 = lane & 15;   // MFMA n index
    const int r4 = r16 & 3;      // real batch row (aliased 4x)
    const int c0 = wave * 32;    // wave's 32 z-cols (cg0: c0.., cg1: c0+16..)
    const int b0 = blockIdx.x * ROWS;

    __shared__ __align__(16) _Float16 Ah[2][ROWS][ASTRIDE];   // 2304 B
    __shared__ __align__(16) int xs[ROWS][XSTR];              // 4160 B
    __shared__ __align__(16) float hfin[ROWS][HIDDEN];        // 2048 B
    __shared__ int lenbuf[ROWS];

    // Stage tokens + lengths; zero both h buffers.
    for (int idx = tid; idx < ROWS * SEQ; idx += 256) {
        int r = idx >> 8, t = idx & (SEQ - 1);
        xs[r][t] = x[(b0 + r) * SEQ + t];
    }
    if (tid < ROWS) lenbuf[tid] = lengths[b0 + tid];
    for (int idx = tid; idx < (int)(sizeof(Ah) / 4); idx += 256)
        ((int*)Ah)[idx] = 0;

    // Static A-frags of W_hh for this wave's two 16-col slices:
    // Wf[cg][kc][j] = W_hh[c0 + cg*16 + r16][kc*32 + q*8 + j]. 32 VGPRs.
    f16x8 Wf[2][4];
#pragma unroll
    for (int cg = 0; cg < 2; ++cg) {
        const float* wrow = W_hh + (c0 + cg * 16 + r16) * HIDDEN + q * 8;
#pragma unroll
        for (int kc = 0; kc < 4; ++kc) {
            const float* p = wrow + kc * 32;
#pragma unroll
            for (int j = 0; j < 8; ++j) Wf[cg][kc][j] = (_Float16)p[j];
        }
    }

    __syncthreads();  // xs / lenbuf visible

    const int mylen = lenbuf[r4];
    const int lenmax = max(max(lenbuf[0], lenbuf[1]), max(lenbuf[2], lenbuf[3]));

    // Per-lane seed base: embW[tok][c0 + 4q .. +3] (cg0), +16 (cg1).
    const float* eb0 = embW + c0 + 4 * q;

    // Prologue: seeds for steps 0,1 (L2-resident, ~200 cyc, hidden by setup).
    int2 tk = *(const int2*)&xs[r4][0];
    f32x4 sa0 = *(const f32x4*)(eb0 + tk.x * HIDDEN);
    f32x4 sb0 = *(const f32x4*)(eb0 + tk.x * HIDDEN + 16);
    f32x4 sa1 = *(const f32x4*)(eb0 + tk.y * HIDDEN);
    f32x4 sb1 = *(const f32x4*)(eb0 + tk.y * HIDDEN + 16);

    int cur = 0;
    f32x4 cap0 = {0.f, 0.f, 0.f, 0.f}, cap1 = {0.f, 0.f, 0.f, 0.f};

// One recurrence step: 4 shared H-reads feed 8 MFMAs (2 cg x 4 k-chunks,
// 4 independent accumulation chains), tanh x8, pack, 2 b64 writes, barrier.
#define STEP(TT, SA, SB) do {                                              \
    const _Float16* hb = &Ah[cur][r4][q * 8];                              \
    f16x8 H0 = *(const f16x8*)(hb + 0);                                    \
    f16x8 H1 = *(const f16x8*)(hb + 32);                                   \
    f16x8 H2 = *(const f16x8*)(hb + 64);                                   \
    f16x8 H3 = *(const f16x8*)(hb + 96);                                   \
    f32x4 a0 = (SA), a1 = (SB);                                            \
    f32x4 d0 = {0.f, 0.f, 0.f, 0.f}, d1 = {0.f, 0.f, 0.f, 0.f};            \
    a0 = MF(Wf[0][0], H0, a0);  a1 = MF(Wf[1][0], H0, a1);                 \
    d0 = MF(Wf[0][2], H2, d0);  d1 = MF(Wf[1][2], H2, d1);                 \
    a0 = MF(Wf[0][1], H1, a0);  a1 = MF(Wf[1][1], H1, a1);                 \
    d0 = MF(Wf[0][3], H3, d0);  d1 = MF(Wf[1][3], H3, d1);                 \
    f32x4 z0 = a0 + d0, z1 = a1 + d1;                                      \
    f32x4 th0, th1;                                                        \
    th0[0] = fast_tanh(z0[0]); th0[1] = fast_tanh(z0[1]);                  \
    th0[2] = fast_tanh(z0[2]); th0[3] = fast_tanh(z0[3]);                  \
    th1[0] = fast_tanh(z1[0]); th1[1] = fast_tanh(z1[1]);                  \
    th1[2] = fast_tanh(z1[2]); th1[3] = fast_tanh(z1[3]);                  \
    uint2 p0, p1;                                                          \
    p0.x = __builtin_bit_cast(unsigned int, __builtin_amdgcn_cvt_pkrtz(th0[0], th0[1])); \
    p0.y = __builtin_bit_cast(unsigned int, __builtin_amdgcn_cvt_pkrtz(th0[2], th0[3])); \
    p1.x = __builtin_bit_cast(unsigned int, __builtin_amdgcn_cvt_pkrtz(th1[0], th1[1])); \
    p1.y = __builtin_bit_cast(unsigned int, __builtin_amdgcn_cvt_pkrtz(th1[2], th1[3])); \
    const int nxt = cur ^ 1;                                               \
    if (r16 < ROWS) {  /* one writer per (row, col-quad) */                \
        *(uint2*)&Ah[nxt][r16][c0 + 4 * q] = p0;                           \
        *(uint2*)&Ah[nxt][r16][c0 + 16 + 4 * q] = p1;                      \
    }                                                                      \
    if ((TT) + 1 == mylen) { cap0 = th0; cap1 = th1; }                     \
    __syncthreads();                                                       \
    cur = nxt;                                                             \
} while (0)

    for (int t0 = 0; t0 < lenmax; t0 += 2) {
        // Prefetch seeds for steps t0+2, t0+3 (VMEM pipe; drains at the step
        // barrier ~300 cyc later -> L2 latency fully hidden). Clamp keeps the
        // token read inside the staged region; garbage steps past lenmax are
        // computed but never captured, and any token is a valid embW row.
        const int tb = min(t0 + 2, SEQ - 2);
        int2 tkn = *(const int2*)&xs[r4][tb];
        f32x4 na0 = *(const f32x4*)(eb0 + tkn.x * HIDDEN);
        f32x4 nb0 = *(const f32x4*)(eb0 + tkn.x * HIDDEN + 16);
        f32x4 na1 = *(const f32x4*)(eb0 + tkn.y * HIDDEN);
        f32x4 nb1 = *(const f32x4*)(eb0 + tkn.y * HIDDEN + 16);

        STEP(t0, sa0, sb0);
        STEP(t0 + 1, sa1, sb1);

        sa0 = na0; sb0 = nb0; sa1 = na1; sb1 = nb1;
    }
#undef STEP

    // Final h (fp32 captures) -> hfin, then FC epilogue.
    if (r16 < ROWS) {
        *(f32x4*)&hfin[r16][c0 + 4 * q] = cap0;
        *(f32x4*)&hfin[r16][c0 + 16 + 4 * q] = cap1;
    }
    __syncthreads();

    // FC: 4 rows x 128 col-slots over 256 threads (2 passes).
    for (int rc = tid; rc < ROWS * 128; rc += 256) {
        const int r = rc >> 7;
        const int c = rc & 127;
        if (c < VOCAB) {
            const float4* hv = (const float4*)hfin[r];
            const float4* wf = (const float4*)(W_fc + c * HIDDEN);
            float a0 = 0.f, a1 = 0.f, a2 = 0.f, a3 = 0.f;
#pragma unroll
            for (int j = 0; j < HIDDEN / 4; ++j) {
                float4 h = hv[j];
                float4 w = wf[j];
                a0 += h.x * w.x; a1 += h.y * w.y; a2 += h.z * w.z; a3 += h.w * w.w;
            }
            out[(b0 + r) * VOCAB + c] = (a0 + a1) + (a2 + a3) + b_fc[c];
        }
    }
}

extern "C" void kernel_launch(void* const* d_in, const int* in_sizes, int n_in,
                              void* d_out, int out_size, void* d_ws, size_t ws_size,
                              hipStream_t stream) {
    const int* x = (const int*)d_in[0];          // [B, T] int32
    const int* lengths = (const int*)d_in[1];    // [B] int32
    const float* emb = (const float*)d_in[2];    // [V, H]
    const float* W_ih = (const float*)d_in[3];   // [H, H]
    const float* W_hh = (const float*)d_in[4];   // [H, H]
    const float* W_fc = (const float*)d_in[5];   // [V, H]
    const float* b_fc = (const float*)d_in[6];   // [V]
    float* out = (float*)d_out;                  // [B, V]

    float* embW = (float*)d_ws;                  // VOCAB*HIDDEN floats (30 KB)

    rnn_prep_embw<<<VOCAB, HIDDEN, 0, stream>>>(emb, W_ih, embW);
    rnn_mfma<<<BATCH / ROWS, 256, 0, stream>>>(x, lengths, embW, W_hh, W_fc, b_fc, out);
}

// Round 3
// 174.713 us; speedup vs baseline: 1.0113x; 1.0113x over previous
//
#include <hip/hip_runtime.h>
#include <hip/hip_bf16.h>

#define BATCH 1024
#define SEQ 256
#define HIDDEN 128
#define VOCAB 60
#define ROWS 4             // real batch rows per block (MFMA n-dim aliased 4x)
#define ASTRIDE 144        // f16 per h row: 72 dw == 8 mod 32 -> max 2-way (free)
#define XSTR 260           // ints per xs row: 260*4B = 1040B, 16B-aligned rows

typedef _Float16 f16x8 __attribute__((ext_vector_type(8)));
typedef float f32x4 __attribute__((ext_vector_type(4)));

__device__ __forceinline__ float fast_tanh(float x) {
    // tanh(x) = 1 - 2/(exp(2x)+1); exp(2x)=exp2(x*2*log2e). Branch-free, exact +-1 tails.
    float e = __builtin_amdgcn_exp2f(x * 2.8853900817779268f);
    return __builtin_fmaf(-2.0f, __builtin_amdgcn_rcpf(e + 1.0f), 1.0f);
}

__device__ __forceinline__ f32x4 MF(f16x8 a, f16x8 b, f32x4 c) {
    return __builtin_amdgcn_mfma_f32_16x16x32_f16(a, b, c, 0, 0, 0);
}

// embW[v][i] = sum_j emb[v][j] * W_ih[i][j]  (fp32-exact input-projection table)
__global__ void rnn_prep_embw(const float* __restrict__ emb,
                              const float* __restrict__ W_ih,
                              float* __restrict__ embW) {
    const int v = blockIdx.x;
    const int i = threadIdx.x;
    __shared__ __align__(16) float e[HIDDEN];
    e[i] = emb[v * HIDDEN + i];
    __syncthreads();
    const float4* wrow = (const float4*)(W_ih + i * HIDDEN);
    const float4* e4 = (const float4*)e;
    float a0 = 0.f, a1 = 0.f, a2 = 0.f, a3 = 0.f;
#pragma unroll
    for (int j = 0; j < HIDDEN / 4; ++j) {
        float4 w = wrow[j];
        float4 h = e4[j];
        a0 += w.x * h.x; a1 += w.y * h.y; a2 += w.z * h.z; a3 += w.w * h.w;
    }
    embW[v * HIDDEN + i] = (a0 + a1) + (a2 + a3);
}

// R18: champion 8-wave structure (512 thr = 2 waves/SIMD for latency hiding;
// R17 proved 1/SIMD exposes the serial chain, +175 cyc/step) + VMEM-seeded
// C-init. The ring/chunk staging is deleted: each step's seed z_in =
// embW[tok][c0+4q..+4) comes from an L2-resident per-lane f32x4 load,
// prefetched 4 steps ahead in named registers. This removes the per-step
// ring ds_read_b128 (8 of 48 DS instrs/step), the boundary reg->ring bursts,
// and the boundary barrier. Tokens read as int4 once per 4 steps. Prefetch
// issues AFTER the first STEP's barrier of each group so the next barrier's
// vmcnt(0) drain lands ~1 step (~850 cyc) after issue - L2 latency hidden.
__global__ void __launch_bounds__(512)
rnn_mfma(const int* __restrict__ x, const int* __restrict__ lengths,
         const float* __restrict__ embW, const float* __restrict__ W_hh,
         const float* __restrict__ W_fc, const float* __restrict__ b_fc,
         float* __restrict__ out) {
    const int tid = threadIdx.x;
    const int wave = tid >> 6;   // 0..7
    const int lane = tid & 63;
    const int q = lane >> 4;     // 0..3
    const int r16 = lane & 15;   // MFMA n index
    const int r4 = r16 & 3;      // real batch row (aliased 4x)
    const int c0 = wave * 16;    // wave's 16 z-cols
    const int b0 = blockIdx.x * ROWS;

    __shared__ __align__(16) _Float16 Ah[2][ROWS][ASTRIDE];   // 2304 B
    __shared__ __align__(16) int xs[ROWS][XSTR];              // 4160 B
    __shared__ __align__(16) float hfin[ROWS][HIDDEN];        // 2048 B
    __shared__ int lenbuf[ROWS];

    // Stage tokens + lengths; zero both h buffers.
    for (int idx = tid; idx < ROWS * SEQ; idx += 512) {
        int r = idx >> 8, t = idx & (SEQ - 1);
        xs[r][t] = x[(b0 + r) * SEQ + t];
    }
    if (tid < ROWS) lenbuf[tid] = lengths[b0 + tid];
    for (int idx = tid; idx < (int)(sizeof(Ah) / 4); idx += 512)
        ((int*)Ah)[idx] = 0;

    // Static A-frags of W_hh for this wave's 16-col slice:
    // A[m=r16][k=kc*32+q*8+j] = W_hh[c0 + r16][kc*32 + q*8 + j]. 16 VGPRs.
    f16x8 Wf[4];
    {
        const float* wrow = W_hh + (c0 + r16) * HIDDEN + q * 8;
#pragma unroll
        for (int kc = 0; kc < 4; ++kc) {
            const float* p = wrow + kc * 32;
#pragma unroll
            for (int j = 0; j < 8; ++j) Wf[kc][j] = (_Float16)p[j];
        }
    }

    __syncthreads();  // xs / lenbuf visible

    const int mylen = lenbuf[r4];
    const int lenmax = max(max(lenbuf[0], lenbuf[1]), max(lenbuf[2], lenbuf[3]));

    // Per-lane seed base: embW[tok][c0 + 4q .. +3].
    const float* eb0 = embW + c0 + 4 * q;

    // Prologue: seeds for steps 0..3 (one-time vmcnt drain, hidden by setup).
    int4 tk = *(const int4*)&xs[r4][0];
    f32x4 s0 = *(const f32x4*)(eb0 + tk.x * HIDDEN);
    f32x4 s1 = *(const f32x4*)(eb0 + tk.y * HIDDEN);
    f32x4 s2 = *(const f32x4*)(eb0 + tk.z * HIDDEN);
    f32x4 s3 = *(const f32x4*)(eb0 + tk.w * HIDDEN);

    int cur = 0;
    f32x4 cap = {0.f, 0.f, 0.f, 0.f};

// One recurrence step: 4 broadcast H-reads feed 4 MFMAs (2 chains), tanh x4,
// pack, 1 b64 write (r16<4 lanes), capture, barrier. Seed comes in SA (regs).
#define STEP(TT, SA) do {                                                  \
    const _Float16* hb = &Ah[cur][r4][q * 8];                              \
    f16x8 H0 = *(const f16x8*)(hb + 0);                                    \
    f16x8 H1 = *(const f16x8*)(hb + 32);                                   \
    f16x8 H2 = *(const f16x8*)(hb + 64);                                   \
    f16x8 H3 = *(const f16x8*)(hb + 96);                                   \
    f32x4 a = (SA);                                                        \
    f32x4 d = {0.f, 0.f, 0.f, 0.f};                                        \
    a = MF(Wf[0], H0, a);                                                  \
    d = MF(Wf[2], H2, d);                                                  \
    a = MF(Wf[1], H1, a);                                                  \
    d = MF(Wf[3], H3, d);                                                  \
    f32x4 z = a + d;                                                       \
    f32x4 th;                                                              \
    th[0] = fast_tanh(z[0]); th[1] = fast_tanh(z[1]);                      \
    th[2] = fast_tanh(z[2]); th[3] = fast_tanh(z[3]);                      \
    uint2 pk;                                                              \
    pk.x = __builtin_bit_cast(unsigned int, __builtin_amdgcn_cvt_pkrtz(th[0], th[1])); \
    pk.y = __builtin_bit_cast(unsigned int, __builtin_amdgcn_cvt_pkrtz(th[2], th[3])); \
    const int nxt = cur ^ 1;                                               \
    if (r16 < ROWS)  /* one writer per (row, col-quad) */                  \
        *(uint2*)&Ah[nxt][r16][c0 + 4 * q] = pk;                           \
    if ((TT) + 1 == mylen) cap = th;                                       \
    __syncthreads();                                                       \
    cur = nxt;                                                             \
} while (0)

    for (int t0 = 0; t0 < lenmax; t0 += 4) {
        STEP(t0, s0);

        // Prefetch seeds for steps t0+4..t0+7 right AFTER a barrier: the
        // next barrier (end of STEP t0+1) is ~1 step away, so its vmcnt(0)
        // drain sees these loads already complete. Clamp keeps the token
        // read in the staged region; extra loads past lenmax are harmless
        // (any token is a valid embW row; never consumed).
        const int tb = min(t0 + 4, SEQ - 4);
        int4 tkn = *(const int4*)&xs[r4][tb];
        f32x4 n0 = *(const f32x4*)(eb0 + tkn.x * HIDDEN);
        f32x4 n1 = *(const f32x4*)(eb0 + tkn.y * HIDDEN);
        f32x4 n2 = *(const f32x4*)(eb0 + tkn.z * HIDDEN);
        f32x4 n3 = *(const f32x4*)(eb0 + tkn.w * HIDDEN);

        // lenmax is block-uniform -> these branches are uniform; the
        // barrier inside STEP executes uniformly or not at all.
        if (t0 + 1 < lenmax) STEP(t0 + 1, s1);
        if (t0 + 2 < lenmax) STEP(t0 + 2, s2);
        if (t0 + 3 < lenmax) STEP(t0 + 3, s3);

        s0 = n0; s1 = n1; s2 = n2; s3 = n3;
    }
#undef STEP

    // Final h (fp32 captures) -> hfin, then FC epilogue.
    if (r16 < ROWS)
        *(f32x4*)&hfin[r16][c0 + 4 * q] = cap;
    __syncthreads();

    // FC: thread (r, c) computes out[b0+r][c].  512 = 4 rows x 128 slots.
    const int r = tid >> 7;      // 0..3
    const int c = tid & 127;     // 0..127
    if (c < VOCAB) {
        const float4* hv = (const float4*)hfin[r];
        const float4* wf = (const float4*)(W_fc + c * HIDDEN);
        float a0 = 0.f, a1 = 0.f, a2 = 0.f, a3 = 0.f;
#pragma unroll
        for (int j = 0; j < HIDDEN / 4; ++j) {
            float4 h = hv[j];
            float4 w = wf[j];
            a0 += h.x * w.x; a1 += h.y * w.y; a2 += h.z * w.z; a3 += h.w * w.w;
        }
        out[(b0 + r) * VOCAB + c] = (a0 + a1) + (a2 + a3) + b_fc[c];
    }
}

extern "C" void kernel_launch(void* const* d_in, const int* in_sizes, int n_in,
                              void* d_out, int out_size, void* d_ws, size_t ws_size,
                              hipStream_t stream) {
    const int* x = (const int*)d_in[0];          // [B, T] int32
    const int* lengths = (const int*)d_in[1];    // [B] int32
    const float* emb = (const float*)d_in[2];    // [V, H]
    const float* W_ih = (const float*)d_in[3];   // [H, H]
    const float* W_hh = (const float*)d_in[4];   // [H, H]
    const float* W_fc = (const float*)d_in[5];   // [V, H]
    const float* b_fc = (const float*)d_in[6];   // [V]
    float* out = (float*)d_out;                  // [B, V]

    float* embW = (float*)d_ws;                  // VOCAB*HIDDEN floats (30 KB)

    rnn_prep_embw<<<VOCAB, HIDDEN, 0, stream>>>(emb, W_ih, embW);
    rnn_mfma<<<BATCH / ROWS, 512, 0, stream>>>(x, lengths, embW, W_hh, W_fc, b_fc, out);
}

// Round 4
// 168.461 us; speedup vs baseline: 1.0488x; 1.0371x over previous
//
#include <hip/hip_runtime.h>
#include <hip/hip_bf16.h>

#define BATCH 1024
#define SEQ 256
#define HIDDEN 128
#define VOCAB 60
#define ROWS 4             // real batch rows per block (MFMA n-dim aliased 4x)
#define ASTRIDE 144        // f16 per h row: 72 dw == 8 mod 32 -> max 2-way (free)
#define XSTR 260           // ints per xs row: 260*4B = 1040B, 16B-aligned rows

typedef _Float16 f16x8 __attribute__((ext_vector_type(8)));
typedef float f32x4 __attribute__((ext_vector_type(4)));

__device__ __forceinline__ float fast_tanh(float x) {
    // tanh(x) = 1 - 2/(exp(2x)+1); exp(2x)=exp2(x*2*log2e). Branch-free, exact +-1 tails.
    float e = __builtin_amdgcn_exp2f(x * 2.8853900817779268f);
    return __builtin_fmaf(-2.0f, __builtin_amdgcn_rcpf(e + 1.0f), 1.0f);
}

__device__ __forceinline__ f32x4 MF(f16x8 a, f16x8 b, f32x4 c) {
    return __builtin_amdgcn_mfma_f32_16x16x32_f16(a, b, c, 0, 0, 0);
}

// Raw step barrier: LDS-write visibility only. __syncthreads() would lower to
// s_waitcnt vmcnt(0) lgkmcnt(0) + s_barrier; the vmcnt(0) force-drains our
// in-flight seed prefetch on the lockstep critical path (R18 post-mortem:
// +140 cyc/step). Cross-wave communication here is LDS-only, so lgkmcnt(0)
// suffices. Memory clobber pins the h-write before / H-reads after.
#define STEP_BARRIER() asm volatile("s_waitcnt lgkmcnt(0)\n\ts_barrier" ::: "memory")

// embW[v][i] = sum_j emb[v][j] * W_ih[i][j]  (fp32-exact input-projection table)
__global__ void rnn_prep_embw(const float* __restrict__ emb,
                              const float* __restrict__ W_ih,
                              float* __restrict__ embW) {
    const int v = blockIdx.x;
    const int i = threadIdx.x;
    __shared__ __align__(16) float e[HIDDEN];
    e[i] = emb[v * HIDDEN + i];
    __syncthreads();
    const float4* wrow = (const float4*)(W_ih + i * HIDDEN);
    const float4* e4 = (const float4*)e;
    float a0 = 0.f, a1 = 0.f, a2 = 0.f, a3 = 0.f;
#pragma unroll
    for (int j = 0; j < HIDDEN / 4; ++j) {
        float4 w = wrow[j];
        float4 h = e4[j];
        a0 += w.x * h.x; a1 += w.y * h.y; a2 += w.z * h.z; a3 += w.w * h.w;
    }
    embW[v * HIDDEN + i] = (a0 + a1) + (a2 + a3);
}

// R19: champion 8-wave structure (512 thr = 2 waves/SIMD; R17 proved 1/SIMD
// exposes the serial chain) + register-resident seeds + raw lgkm-only step
// barrier. Ring/chunk machinery deleted: seeds live in 16 VGPRs, prefetched
// 4 steps (~3400 cyc) ahead from L2/L1-resident embW; the raw barrier never
// drains vmcnt, so the loads coast until their compiler-inserted vmcnt(k)
// wait, which is long satisfied. DS ops/step: 40 (32 H-reads + 8 h-writes).
__global__ void __launch_bounds__(512)
rnn_mfma(const int* __restrict__ x, const int* __restrict__ lengths,
         const float* __restrict__ embW, const float* __restrict__ W_hh,
         const float* __restrict__ W_fc, const float* __restrict__ b_fc,
         float* __restrict__ out) {
    const int tid = threadIdx.x;
    const int wave = tid >> 6;   // 0..7
    const int lane = tid & 63;
    const int q = lane >> 4;     // 0..3
    const int r16 = lane & 15;   // MFMA n index
    const int r4 = r16 & 3;      // real batch row (aliased 4x)
    const int c0 = wave * 16;    // wave's 16 z-cols
    const int b0 = blockIdx.x * ROWS;

    __shared__ __align__(16) _Float16 Ah[2][ROWS][ASTRIDE];   // 2304 B
    __shared__ __align__(16) int xs[ROWS][XSTR];              // 4160 B
    __shared__ __align__(16) float hfin[ROWS][HIDDEN];        // 2048 B
    __shared__ int lenbuf[ROWS];

    // Stage tokens + lengths; zero both h buffers.
    for (int idx = tid; idx < ROWS * SEQ; idx += 512) {
        int r = idx >> 8, t = idx & (SEQ - 1);
        xs[r][t] = x[(b0 + r) * SEQ + t];
    }
    if (tid < ROWS) lenbuf[tid] = lengths[b0 + tid];
    for (int idx = tid; idx < (int)(sizeof(Ah) / 4); idx += 512)
        ((int*)Ah)[idx] = 0;

    // Static A-frags of W_hh for this wave's 16-col slice:
    // A[m=r16][k=kc*32+q*8+j] = W_hh[c0 + r16][kc*32 + q*8 + j]. 16 VGPRs.
    f16x8 Wf[4];
    {
        const float* wrow = W_hh + (c0 + r16) * HIDDEN + q * 8;
#pragma unroll
        for (int kc = 0; kc < 4; ++kc) {
            const float* p = wrow + kc * 32;
#pragma unroll
            for (int j = 0; j < 8; ++j) Wf[kc][j] = (_Float16)p[j];
        }
    }

    __syncthreads();  // xs / lenbuf / Ah visible (full sync once; cost amortized)

    const int mylen = lenbuf[r4];
    const int lenmax = max(max(lenbuf[0], lenbuf[1]), max(lenbuf[2], lenbuf[3]));
    const int lenpad = (lenmax + 3) & ~3;   // pad to x4: extra steps compute
                                            // garbage h, never captured.

    // Per-lane seed base: embW[tok][c0 + 4q .. +3].
    const float* eb0 = embW + c0 + 4 * q;

    // Prologue: seeds for steps 0..3.
    int4 tk = *(const int4*)&xs[r4][0];
    f32x4 s0 = *(const f32x4*)(eb0 + tk.x * HIDDEN);
    f32x4 s1 = *(const f32x4*)(eb0 + tk.y * HIDDEN);
    f32x4 s2 = *(const f32x4*)(eb0 + tk.z * HIDDEN);
    f32x4 s3 = *(const f32x4*)(eb0 + tk.w * HIDDEN);

    int cur = 0;
    f32x4 cap = {0.f, 0.f, 0.f, 0.f};

// One recurrence step: 4 broadcast H-reads feed 4 MFMAs (2 chains), tanh x4,
// pack, 1 b64 write (r16<4 lanes), capture, raw lgkm-only barrier.
#define STEP(TT, SA) do {                                                  \
    const _Float16* hb = &Ah[cur][r4][q * 8];                              \
    f16x8 H0 = *(const f16x8*)(hb + 0);                                    \
    f16x8 H1 = *(const f16x8*)(hb + 32);                                   \
    f16x8 H2 = *(const f16x8*)(hb + 64);                                   \
    f16x8 H3 = *(const f16x8*)(hb + 96);                                   \
    f32x4 a = (SA);                                                        \
    f32x4 d = {0.f, 0.f, 0.f, 0.f};                                        \
    a = MF(Wf[0], H0, a);                                                  \
    d = MF(Wf[2], H2, d);                                                  \
    a = MF(Wf[1], H1, a);                                                  \
    d = MF(Wf[3], H3, d);                                                  \
    f32x4 z = a + d;                                                       \
    f32x4 th;                                                              \
    th[0] = fast_tanh(z[0]); th[1] = fast_tanh(z[1]);                      \
    th[2] = fast_tanh(z[2]); th[3] = fast_tanh(z[3]);                      \
    uint2 pk;                                                              \
    pk.x = __builtin_bit_cast(unsigned int, __builtin_amdgcn_cvt_pkrtz(th[0], th[1])); \
    pk.y = __builtin_bit_cast(unsigned int, __builtin_amdgcn_cvt_pkrtz(th[2], th[3])); \
    const int nxt = cur ^ 1;                                               \
    if (r16 < ROWS)  /* one writer per (row, col-quad) */                  \
        *(uint2*)&Ah[nxt][r16][c0 + 4 * q] = pk;                           \
    if ((TT) + 1 == mylen) cap = th;                                       \
    STEP_BARRIER();                                                        \
    cur = nxt;                                                             \
} while (0)

    for (int t0 = 0; t0 < lenpad; t0 += 4) {
        STEP(t0, s0);

        // Prefetch seeds for steps t0+4..t0+7 right after a barrier. The raw
        // barriers never drain vmcnt, so these have ~3 steps (~2500 cyc) to
        // complete before their compiler-inserted vmcnt wait at consumption.
        // Clamp keeps the token read in the staged region; loads past lenmax
        // fetch valid-but-unused embW rows (harmless).
        const int tb = min(t0 + 4, SEQ - 4);
        int4 tkn = *(const int4*)&xs[r4][tb];
        f32x4 n0 = *(const f32x4*)(eb0 + tkn.x * HIDDEN);
        f32x4 n1 = *(const f32x4*)(eb0 + tkn.y * HIDDEN);
        f32x4 n2 = *(const f32x4*)(eb0 + tkn.z * HIDDEN);
        f32x4 n3 = *(const f32x4*)(eb0 + tkn.w * HIDDEN);

        STEP(t0 + 1, s1);
        STEP(t0 + 2, s2);
        STEP(t0 + 3, s3);

        s0 = n0; s1 = n1; s2 = n2; s3 = n3;
    }
#undef STEP

    // Final h (fp32 captures) -> hfin, then FC epilogue.
    if (r16 < ROWS)
        *(f32x4*)&hfin[r16][c0 + 4 * q] = cap;
    __syncthreads();

    // FC: thread (r, c) computes out[b0+r][c].  512 = 4 rows x 128 slots.
    const int r = tid >> 7;      // 0..3
    const int c = tid & 127;     // 0..127
    if (c < VOCAB) {
        const float4* hv = (const float4*)hfin[r];
        const float4* wf = (const float4*)(W_fc + c * HIDDEN);
        float a0 = 0.f, a1 = 0.f, a2 = 0.f, a3 = 0.f;
#pragma unroll
        for (int j = 0; j < HIDDEN / 4; ++j) {
            float4 h = hv[j];
            float4 w = wf[j];
            a0 += h.x * w.x; a1 += h.y * w.y; a2 += h.z * w.z; a3 += h.w * w.w;
        }
        out[(b0 + r) * VOCAB + c] = (a0 + a1) + (a2 + a3) + b_fc[c];
    }
}

extern "C" void kernel_launch(void* const* d_in, const int* in_sizes, int n_in,
                              void* d_out, int out_size, void* d_ws, size_t ws_size,
                              hipStream_t stream) {
    const int* x = (const int*)d_in[0];          // [B, T] int32
    const int* lengths = (const int*)d_in[1];    // [B] int32
    const float* emb = (const float*)d_in[2];    // [V, H]
    const float* W_ih = (const float*)d_in[3];   // [H, H]
    const float* W_hh = (const float*)d_in[4];   // [H, H]
    const float* W_fc = (const float*)d_in[5];   // [V, H]
    const float* b_fc = (const float*)d_in[6];   // [V]
    float* out = (float*)d_out;                  // [B, V]

    float* embW = (float*)d_ws;                  // VOCAB*HIDDEN floats (30 KB)

    rnn_prep_embw<<<VOCAB, HIDDEN, 0, stream>>>(emb, W_ih, embW);
    rnn_mfma<<<BATCH / ROWS, 512, 0, stream>>>(x, lengths, embW, W_hh, W_fc, b_fc, out);
}